// Round 10
// baseline (200.806 us; speedup 1.0000x reference)
//
#include <hip/hip_runtime.h>
#include <hip/hip_bf16.h>
#include <cstdint>

// ---------------------------------------------------------------------------
// Fused causal self-attention block (B=2, T=2048, C=1024, H=16, Dh=64), fp32 in/out.
// cvt fp32->bf16 -> QKV GEMM (Q pre-scaled) -> V-transpose -> causal flash attn -> out GEMM.
// Workspace (48MB):
//   xb/Vt @ 0     8 MB   bf16 x [4096][1024]; REUSED after gemm1 as Vt [32][64][2048]
//   wqkvb @ 8 MB  6 MB   bf16 w_qkv [3072][1024]
//   wob   @ 14MB  2 MB   bf16 w_out [1024][1024]
//   qkvb  @ 16MB 24 MB   bf16 qkv [4096][3072] (Q|K|V; Q scaled by 0.125*log2e)
//   yb    @ 40MB  8 MB   bf16 attn out [4096][1024]
// ---------------------------------------------------------------------------

typedef __bf16 bf16x8 __attribute__((ext_vector_type(8)));
typedef __bf16 bf16x2 __attribute__((ext_vector_type(2)));
typedef float  f32x4  __attribute__((ext_vector_type(4)));

#define EMB   1024
#define HEADS 16
#define HD    64
#define TT    2048
#define NROWS 4096
#define QKVN  3072
#define SCL   0.18033688f   /* 0.125 * log2(e): folded into Q at gemm1 epilogue */
#define THR   11.0f         /* defer-max threshold, log2 units */

// ---- fused fp32 -> bf16 (8 elems / thread, 3 arrays in one launch) ----
__global__ void cvt_all(const float* __restrict__ x, const float* __restrict__ wq,
                        const float* __restrict__ wo, __bf16* __restrict__ xb,
                        __bf16* __restrict__ wqb, __bf16* __restrict__ wob) {
  const int bid = blockIdx.x;
  const float* in; __bf16* out; int i;
  if (bid < 2048)      { in = x;  out = xb;  i = bid * 256 + threadIdx.x; }
  else if (bid < 3584) { in = wq; out = wqb; i = (bid - 2048) * 256 + threadIdx.x; }
  else                 { in = wo; out = wob; i = (bid - 3584) * 256 + threadIdx.x; }
  const float4* p = (const float4*)in + (size_t)i * 2;
  float4 a = p[0], b = p[1];
  bf16x8 o;
  o[0] = (__bf16)a.x; o[1] = (__bf16)a.y; o[2] = (__bf16)a.z; o[3] = (__bf16)a.w;
  o[4] = (__bf16)b.x; o[5] = (__bf16)b.y; o[6] = (__bf16)b.z; o[7] = (__bf16)b.w;
  *((bf16x8*)out + i) = o;
}

__device__ __forceinline__ void gload_lds16(const void* g, void* l) {
  __builtin_amdgcn_global_load_lds(
      (const __attribute__((address_space(1))) void*)(uintptr_t)g,
      (__attribute__((address_space(3))) void*)(uint32_t)(uintptr_t)l,
      16, 0, 0);
}

// ---- GEMM: C[M,N] = A[M,K] * Bm[N,K]^T (m97 structure + XCD swizzle) ----
template <int OUT_BF16, int SCALE_Q>
__global__ __launch_bounds__(256, 2)
void gemm_bt(const __bf16* __restrict__ A, const __bf16* __restrict__ Bm,
             void* __restrict__ Cout, int M, int N, int K) {
  __shared__ __align__(16) __bf16 As[128 * 32];
  __shared__ __align__(16) __bf16 Bs[128 * 32];
  const int tid  = threadIdx.x;
  const int lane = tid & 63;
  const int wid  = tid >> 6;
  const int wr = wid >> 1, wc = wid & 1;
  const int nwg = gridDim.x * gridDim.y;
  int flat = blockIdx.y * gridDim.x + blockIdx.x;
  flat = (flat & 7) * (nwg >> 3) + (flat >> 3);
  const int brow = (flat / gridDim.x) * 128;
  const int bcol = (flat % gridDim.x) * 128;
  const int fr = lane & 15, g = lane >> 4;

  f32x4 acc[4][4];
#pragma unroll
  for (int m = 0; m < 4; m++)
#pragma unroll
    for (int n = 0; n < 4; n++)
#pragma unroll
      for (int r = 0; r < 4; r++) acc[m][n][r] = 0.0f;

  const int c0 = tid, c1 = tid + 256;
  for (int k0 = 0; k0 < K; k0 += 32) {
    __syncthreads();
    gload_lds16(A  + (size_t)(brow + (c0 >> 2)) * K + k0 + (c0 & 3) * 8, (char*)As + c0 * 16);
    gload_lds16(A  + (size_t)(brow + (c1 >> 2)) * K + k0 + (c1 & 3) * 8, (char*)As + c1 * 16);
    gload_lds16(Bm + (size_t)(bcol + (c0 >> 2)) * K + k0 + (c0 & 3) * 8, (char*)Bs + c0 * 16);
    gload_lds16(Bm + (size_t)(bcol + (c1 >> 2)) * K + k0 + (c1 & 3) * 8, (char*)Bs + c1 * 16);
    __syncthreads();

    bf16x8 af[4], bfr[4];
#pragma unroll
    for (int m = 0; m < 4; m++)
      af[m] = *(const bf16x8*)((const char*)As + (wr * 64 + m * 16 + fr) * 64 + g * 16);
#pragma unroll
    for (int n = 0; n < 4; n++)
      bfr[n] = *(const bf16x8*)((const char*)Bs + (wc * 64 + n * 16 + fr) * 64 + g * 16);
#pragma unroll
    for (int m = 0; m < 4; m++)
#pragma unroll
      for (int n = 0; n < 4; n++)
        acc[m][n] = __builtin_amdgcn_mfma_f32_16x16x32_bf16(af[m], bfr[n], acc[m][n], 0, 0, 0);
  }

  const float qscale = (SCALE_Q && bcol < EMB) ? SCL : 1.0f;
  const int rbase = brow + wr * 64 + g * 4;
  const int cbase = bcol + wc * 64 + fr;
#pragma unroll
  for (int m = 0; m < 4; m++)
#pragma unroll
    for (int n = 0; n < 4; n++) {
      const int col = cbase + n * 16;
#pragma unroll
      for (int r = 0; r < 4; r++) {
        const int row = rbase + m * 16 + r;
        const float v = acc[m][n][r] * qscale;
        if (OUT_BF16) ((__bf16*)Cout)[(size_t)row * N + col] = (__bf16)v;
        else          ((float*)Cout)[(size_t)row * N + col]  = v;
      }
    }
}

// ---- V transpose: qkv [4096][3072] (V cols) -> Vt [32 bh][64 d][2048 t] ----
__global__ __launch_bounds__(256)
void vtrans(const __bf16* __restrict__ qkv, __bf16* __restrict__ vt) {
  __shared__ __bf16 tile[64][66];
  const int tt = blockIdx.x;
  const int bh = blockIdx.y;
  const int b = bh >> 4, h = bh & 15;
  const int tid = threadIdx.x;
  const int tl = tid >> 2, dq = (tid & 3) * 16;
  const __bf16* src = qkv + ((size_t)(b * TT + tt * 64 + tl)) * QKVN + 2 * EMB + h * HD + dq;
  bf16x8 v0 = *(const bf16x8*)src;
  bf16x8 v1 = *(const bf16x8*)(src + 8);
#pragma unroll
  for (int u = 0; u < 4; u++) {
    *(bf16x2*)&tile[tl][dq + 2 * u]     = bf16x2{v0[2 * u], v0[2 * u + 1]};
    *(bf16x2*)&tile[tl][dq + 8 + 2 * u] = bf16x2{v1[2 * u], v1[2 * u + 1]};
  }
  __syncthreads();
  const int d = tid >> 2, tc = (tid & 3) * 16;
  bf16x8 o0, o1;
#pragma unroll
  for (int j = 0; j < 8; j++) { o0[j] = tile[tc + j][d]; o1[j] = tile[tc + 8 + j][d]; }
  __bf16* dst = vt + ((size_t)bh * HD + d) * TT + tt * 64 + tc;
  *(bf16x8*)dst = o0;
  *(bf16x8*)(dst + 8) = o1;
}

// ---------------------------------------------------------------------------
// Causal flash attention v10: barrier-free dataflow.
//   - 1-wave blocks (64 thr), 32 q-rows per wave; grid 2048 = 64 pos x 32 bh.
//     NO __syncthreads anywhere: waves progress independently, stalls
//     decorrelate; 8 blocks/CU resident.
//   - K and Vt read DIRECTLY from global (L2-resident: 512KB/bh, 4 bh/XCD
//     = 2MB < 4MB L2). No LDS staging, no vmcnt choreography (m169 lesson).
//   - 1-deep in-wave pipeline: iter t issues loads(t+1), runs PV(t), then
//     QK(t+1)+softmax(t+1). L2 latency hides under PV+softmax; no barrier
//     can interrupt the overlap. vb ping-pong (static names), single kf.
//   - P via wave-private 4KB LDS (psw swizzle); defer-max; ones-MFMA lacc;
//     raw v_exp_f32; Q pre-scaled. LPT order (longest chunk first).
// ---------------------------------------------------------------------------
__device__ __forceinline__ int psw(int row) {
  return (((row & 7) ^ ((row >> 3) & 7))) << 4;
}

__global__ __launch_bounds__(64, 2)
void attn_causal10(const __bf16* __restrict__ qkv, const __bf16* __restrict__ vt,
                   __bf16* __restrict__ yb) {
  __shared__ __align__(16) char Pbuf[4096];      // P[32][64] bf16, psw-swizzled

  const int lane = threadIdx.x;
  const int L = blockIdx.x;
  const int bh = L & 31;
  const int p = 63 - (L >> 5);                   // LPT: longest first
  const int b = bh >> 4, h = bh & 15;
  const size_t rowbase = (size_t)b * TT;
  const int q0 = p * 32;
  const int fr = lane & 15, g = lane >> 4;
  const int ntiles = (p >> 1) + 1;
  const int lt = ntiles - 1;

  // Q fragments (pre-scaled by SCL): rows q0+m*16+fr, d = kc*32+g*8
  bf16x8 qf[2][2];
#pragma unroll
  for (int m2 = 0; m2 < 2; m2++)
#pragma unroll
    for (int kc = 0; kc < 2; kc++)
      qf[m2][kc] = *(const bf16x8*)(qkv + (rowbase + q0 + m2 * 16 + fr) * QKVN + h * HD + kc * 32 + g * 8);

  bf16x8 ones;
#pragma unroll
  for (int j = 0; j < 8; j++) ones[j] = (__bf16)1.0f;

  // per-lane K / Vt row base pointers (4 rows each; kc via +32 imm offset)
  const __bf16* kp[4];
  const __bf16* vp[4];
#pragma unroll
  for (int n = 0; n < 4; n++) {
    kp[n] = qkv + (rowbase + n * 16 + fr) * QKVN + EMB + h * HD + g * 8;
    vp[n] = vt + ((size_t)bh * HD + n * 16 + fr) * TT + g * 8;
  }

  f32x4 o[2][4];
  f32x4 lacc[2];
  float m[2][4];
#pragma unroll
  for (int m2 = 0; m2 < 2; m2++) {
#pragma unroll
    for (int n = 0; n < 4; n++)
#pragma unroll
      for (int r = 0; r < 4; r++) o[m2][n][r] = 0.0f;
#pragma unroll
    for (int r = 0; r < 4; r++) { lacc[m2][r] = 0.0f; m[m2][r] = -1e30f; }
  }

  auto loadK = [&](int t, bf16x8 (&kf)[4][2]) {
    const size_t off = (size_t)(t * 64) * QKVN;
#pragma unroll
    for (int n = 0; n < 4; n++) {
      kf[n][0] = *(const bf16x8*)(kp[n] + off);
      kf[n][1] = *(const bf16x8*)(kp[n] + off + 32);
    }
  };
  auto loadV = [&](int t, bf16x8 (&vb)[4][2]) {
    const int off = t * 64;
#pragma unroll
    for (int n = 0; n < 4; n++) {
      vb[n][0] = *(const bf16x8*)(vp[n] + off);
      vb[n][1] = *(const bf16x8*)(vp[n] + off + 32);
    }
  };

  auto doQK = [&](bf16x8 (&kf)[4][2], f32x4 (&s)[2][4]) {
#pragma unroll
    for (int m2 = 0; m2 < 2; m2++)
#pragma unroll
      for (int n = 0; n < 4; n++) {
        f32x4 z;
#pragma unroll
        for (int r = 0; r < 4; r++) z[r] = 0.0f;
        z = __builtin_amdgcn_mfma_f32_16x16x32_bf16(qf[m2][0], kf[n][0], z, 0, 0, 0);
        s[m2][n] = __builtin_amdgcn_mfma_f32_16x16x32_bf16(qf[m2][1], kf[n][1], z, 0, 0, 0);
      }
  };

  auto doSM = [&](int t, f32x4 (&s)[2][4]) {
    const int kv0 = t * 64;
    if (t == lt) {                               // causal mask (last tile only)
#pragma unroll
      for (int m2 = 0; m2 < 2; m2++)
#pragma unroll
        for (int n = 0; n < 4; n++)
#pragma unroll
          for (int r = 0; r < 4; r++) {
            const int qg = q0 + m2 * 16 + g * 4 + r;
            const int kg = kv0 + n * 16 + fr;
            if (kg > qg) s[m2][n][r] = -1e30f;
          }
    }
    float pm[2][4];
#pragma unroll
    for (int m2 = 0; m2 < 2; m2++)
#pragma unroll
      for (int r = 0; r < 4; r++)
        pm[m2][r] = fmaxf(fmaxf(s[m2][0][r], s[m2][1][r]), fmaxf(s[m2][2][r], s[m2][3][r]));
    bool okl = true;
#pragma unroll
    for (int m2 = 0; m2 < 2; m2++)
#pragma unroll
      for (int r = 0; r < 4; r++)
        okl = okl && (pm[m2][r] <= m[m2][r] + THR);
    if (!__all(okl)) {
#pragma unroll
      for (int m2 = 0; m2 < 2; m2++)
#pragma unroll
        for (int r = 0; r < 4; r++) {
          float rm = pm[m2][r];
#pragma unroll
          for (int d = 1; d < 16; d <<= 1) rm = fmaxf(rm, __shfl_xor(rm, d, 16));
          const float nm = fmaxf(m[m2][r], rm);
          const float f = __builtin_amdgcn_exp2f(m[m2][r] - nm);
          m[m2][r] = nm;
          lacc[m2][r] *= f;
#pragma unroll
          for (int n = 0; n < 4; n++) o[m2][n][r] *= f;
        }
    }
#pragma unroll
    for (int m2 = 0; m2 < 2; m2++)
#pragma unroll
      for (int n = 0; n < 4; n++)
#pragma unroll
        for (int r = 0; r < 4; r++) {
          const float e = __builtin_amdgcn_exp2f(s[m2][n][r] - m[m2][r]);
          const int row = m2 * 16 + g * 4 + r;
          *(__bf16*)(Pbuf + row * 128 + (((n * 16 + fr) * 2) ^ psw(row))) = (__bf16)e;
        }
  };

  auto doPV = [&](bf16x8 (&vb)[4][2]) {
    bf16x8 pa[2][2];
#pragma unroll
    for (int m2 = 0; m2 < 2; m2++)
#pragma unroll
      for (int kc = 0; kc < 2; kc++) {
        const int row = m2 * 16 + fr;
        pa[m2][kc] = *(const bf16x8*)(Pbuf + row * 128 + ((kc * 64 + g * 16) ^ psw(row)));
      }
#pragma unroll
    for (int m2 = 0; m2 < 2; m2++) {
#pragma unroll
      for (int kc = 0; kc < 2; kc++) {
        lacc[m2] = __builtin_amdgcn_mfma_f32_16x16x32_bf16(pa[m2][kc], ones, lacc[m2], 0, 0, 0);
#pragma unroll
        for (int n = 0; n < 4; n++)
          o[m2][n] = __builtin_amdgcn_mfma_f32_16x16x32_bf16(pa[m2][kc], vb[n][kc], o[m2][n], 0, 0, 0);
      }
    }
  };

  // ---- prologue: tile 0 (QK + softmax; P(0) ready, V(0) in vbA) ----
  bf16x8 kf[4][2], vbA[4][2], vbB[4][2];
  f32x4 s[2][4];
  loadK(0, kf);
  loadV(0, vbA);
  doQK(kf, s);
  doSM(0, s);

  // ---- main loop: 2x unrolled ping-pong on vb (static reg names) ----
  int t = 0;
  while (true) {
    {
      const bool nxt = (t + 1 < ntiles);
      if (nxt) { loadK(t + 1, kf); loadV(t + 1, vbB); }  // issue early (T14)
      doPV(vbA);                                          // consumes P(t), V(t)
      if (nxt) { doQK(kf, s); doSM(t + 1, s); }           // writes P(t+1)
      if (++t >= ntiles) break;
    }
    {
      const bool nxt = (t + 1 < ntiles);
      if (nxt) { loadK(t + 1, kf); loadV(t + 1, vbA); }
      doPV(vbB);
      if (nxt) { doQK(kf, s); doSM(t + 1, s); }
      if (++t >= ntiles) break;
    }
  }

  // ---- epilogue: normalize + store ----
#pragma unroll
  for (int m2 = 0; m2 < 2; m2++)
#pragma unroll
    for (int r = 0; r < 4; r++) {
      const float inv = __builtin_amdgcn_rcpf(lacc[m2][r]);
      const int q = q0 + m2 * 16 + g * 4 + r;
#pragma unroll
      for (int n = 0; n < 4; n++) {
        const int d = n * 16 + fr;
        yb[(rowbase + q) * EMB + h * HD + d] = (__bf16)(o[m2][n][r] * inv);
      }
    }
}

extern "C" void kernel_launch(void* const* d_in, const int* in_sizes, int n_in,
                              void* d_out, int out_size, void* d_ws, size_t ws_size,
                              hipStream_t stream) {
  const float* x     = (const float*)d_in[0];
  const float* w_qkv = (const float*)d_in[1];
  const float* w_out = (const float*)d_in[2];
  float* out = (float*)d_out;

  char* ws = (char*)d_ws;
  __bf16* xb    = (__bf16*)(ws);                 // reused as Vt after gemm1
  __bf16* wqkvb = (__bf16*)(ws + (8ull  << 20));
  __bf16* wob   = (__bf16*)(ws + (14ull << 20));
  __bf16* qkvb  = (__bf16*)(ws + (16ull << 20));
  __bf16* yb    = (__bf16*)(ws + (40ull << 20));
  __bf16* vtb   = xb;

  cvt_all<<<4096, 256, 0, stream>>>(x, w_qkv, w_out, xb, wqkvb, wob);
  gemm_bt<1, 1><<<dim3(QKVN / 128, NROWS / 128), 256, 0, stream>>>(xb, wqkvb, qkvb, NROWS, QKVN, EMB);
  vtrans<<<dim3(TT / 64, 32), 256, 0, stream>>>(qkvb, vtb);
  attn_causal10<<<2048, 64, 0, stream>>>(qkvb, vtb, yb);
  gemm_bt<0, 0><<<dim3(EMB / 128, NROWS / 128), 256, 0, stream>>>(yb, wob, out, NROWS, EMB, EMB);
}

// Round 11
// 177.041 us; speedup vs baseline: 1.1342x; 1.1342x over previous
//
#include <hip/hip_runtime.h>
#include <hip/hip_bf16.h>
#include <cstdint>

// ---------------------------------------------------------------------------
// Fused causal self-attention block (B=2, T=2048, C=1024, H=16, Dh=64), fp32 in/out.
// cvt fp32->bf16 -> QKV GEMM (Q pre-scaled) -> V-transpose -> causal flash attn -> out GEMM.
// Workspace (48MB):
//   xb/Vt @ 0     8 MB   bf16 x [4096][1024]; REUSED after gemm1 as Vt [32][64][2048]
//   wqkvb @ 8 MB  6 MB   bf16 w_qkv [3072][1024]
//   wob   @ 14MB  2 MB   bf16 w_out [1024][1024]
//   qkvb  @ 16MB 24 MB   bf16 qkv [4096][3072] (Q|K|V; Q scaled by 0.125*log2e)
//   yb    @ 40MB  8 MB   bf16 attn out [4096][1024]
// ---------------------------------------------------------------------------

typedef __bf16 bf16x8 __attribute__((ext_vector_type(8)));
typedef __bf16 bf16x2 __attribute__((ext_vector_type(2)));
typedef float  f32x4  __attribute__((ext_vector_type(4)));

#define EMB   1024
#define HEADS 16
#define HD    64
#define TT    2048
#define NROWS 4096
#define QKVN  3072
#define SCL   0.18033688f   /* 0.125 * log2(e): folded into Q at gemm1 epilogue */
#define THR   11.0f         /* defer-max threshold, log2 units */

// ---- fused fp32 -> bf16 (8 elems / thread, 3 arrays in one launch) ----
__global__ void cvt_all(const float* __restrict__ x, const float* __restrict__ wq,
                        const float* __restrict__ wo, __bf16* __restrict__ xb,
                        __bf16* __restrict__ wqb, __bf16* __restrict__ wob) {
  const int bid = blockIdx.x;
  const float* in; __bf16* out; int i;
  if (bid < 2048)      { in = x;  out = xb;  i = bid * 256 + threadIdx.x; }
  else if (bid < 3584) { in = wq; out = wqb; i = (bid - 2048) * 256 + threadIdx.x; }
  else                 { in = wo; out = wob; i = (bid - 3584) * 256 + threadIdx.x; }
  const float4* p = (const float4*)in + (size_t)i * 2;
  float4 a = p[0], b = p[1];
  bf16x8 o;
  o[0] = (__bf16)a.x; o[1] = (__bf16)a.y; o[2] = (__bf16)a.z; o[3] = (__bf16)a.w;
  o[4] = (__bf16)b.x; o[5] = (__bf16)b.y; o[6] = (__bf16)b.z; o[7] = (__bf16)b.w;
  *((bf16x8*)out + i) = o;
}

__device__ __forceinline__ void gload_lds16(const void* g, void* l) {
  __builtin_amdgcn_global_load_lds(
      (const __attribute__((address_space(1))) void*)(uintptr_t)g,
      (__attribute__((address_space(3))) void*)(uint32_t)(uintptr_t)l,
      16, 0, 0);
}

// ---- GEMM: C[M,N] = A[M,K] * Bm[N,K]^T (m97 structure + XCD swizzle) ----
template <int OUT_BF16, int SCALE_Q>
__global__ __launch_bounds__(256, 2)
void gemm_bt(const __bf16* __restrict__ A, const __bf16* __restrict__ Bm,
             void* __restrict__ Cout, int M, int N, int K) {
  __shared__ __align__(16) __bf16 As[128 * 32];
  __shared__ __align__(16) __bf16 Bs[128 * 32];
  const int tid  = threadIdx.x;
  const int lane = tid & 63;
  const int wid  = tid >> 6;
  const int wr = wid >> 1, wc = wid & 1;
  const int nwg = gridDim.x * gridDim.y;
  int flat = blockIdx.y * gridDim.x + blockIdx.x;
  flat = (flat & 7) * (nwg >> 3) + (flat >> 3);
  const int brow = (flat / gridDim.x) * 128;
  const int bcol = (flat % gridDim.x) * 128;
  const int fr = lane & 15, g = lane >> 4;

  f32x4 acc[4][4];
#pragma unroll
  for (int m = 0; m < 4; m++)
#pragma unroll
    for (int n = 0; n < 4; n++)
#pragma unroll
      for (int r = 0; r < 4; r++) acc[m][n][r] = 0.0f;

  const int c0 = tid, c1 = tid + 256;
  for (int k0 = 0; k0 < K; k0 += 32) {
    __syncthreads();
    gload_lds16(A  + (size_t)(brow + (c0 >> 2)) * K + k0 + (c0 & 3) * 8, (char*)As + c0 * 16);
    gload_lds16(A  + (size_t)(brow + (c1 >> 2)) * K + k0 + (c1 & 3) * 8, (char*)As + c1 * 16);
    gload_lds16(Bm + (size_t)(bcol + (c0 >> 2)) * K + k0 + (c0 & 3) * 8, (char*)Bs + c0 * 16);
    gload_lds16(Bm + (size_t)(bcol + (c1 >> 2)) * K + k0 + (c1 & 3) * 8, (char*)Bs + c1 * 16);
    __syncthreads();

    bf16x8 af[4], bfr[4];
#pragma unroll
    for (int m = 0; m < 4; m++)
      af[m] = *(const bf16x8*)((const char*)As + (wr * 64 + m * 16 + fr) * 64 + g * 16);
#pragma unroll
    for (int n = 0; n < 4; n++)
      bfr[n] = *(const bf16x8*)((const char*)Bs + (wc * 64 + n * 16 + fr) * 64 + g * 16);
#pragma unroll
    for (int m = 0; m < 4; m++)
#pragma unroll
      for (int n = 0; n < 4; n++)
        acc[m][n] = __builtin_amdgcn_mfma_f32_16x16x32_bf16(af[m], bfr[n], acc[m][n], 0, 0, 0);
  }

  const float qscale = (SCALE_Q && bcol < EMB) ? SCL : 1.0f;
  const int rbase = brow + wr * 64 + g * 4;
  const int cbase = bcol + wc * 64 + fr;
#pragma unroll
  for (int m = 0; m < 4; m++)
#pragma unroll
    for (int n = 0; n < 4; n++) {
      const int col = cbase + n * 16;
#pragma unroll
      for (int r = 0; r < 4; r++) {
        const int row = rbase + m * 16 + r;
        const float v = acc[m][n][r] * qscale;
        if (OUT_BF16) ((__bf16*)Cout)[(size_t)row * N + col] = (__bf16)v;
        else          ((float*)Cout)[(size_t)row * N + col]  = v;
      }
    }
}

// ---- V transpose: qkv [4096][3072] (V cols) -> Vt [32 bh][64 d][2048 t] ----
__global__ __launch_bounds__(256)
void vtrans(const __bf16* __restrict__ qkv, __bf16* __restrict__ vt) {
  __shared__ __bf16 tile[64][66];
  const int tt = blockIdx.x;
  const int bh = blockIdx.y;
  const int b = bh >> 4, h = bh & 15;
  const int tid = threadIdx.x;
  const int tl = tid >> 2, dq = (tid & 3) * 16;
  const __bf16* src = qkv + ((size_t)(b * TT + tt * 64 + tl)) * QKVN + 2 * EMB + h * HD + dq;
  bf16x8 v0 = *(const bf16x8*)src;
  bf16x8 v1 = *(const bf16x8*)(src + 8);
#pragma unroll
  for (int u = 0; u < 4; u++) {
    *(bf16x2*)&tile[tl][dq + 2 * u]     = bf16x2{v0[2 * u], v0[2 * u + 1]};
    *(bf16x2*)&tile[tl][dq + 8 + 2 * u] = bf16x2{v1[2 * u], v1[2 * u + 1]};
  }
  __syncthreads();
  const int d = tid >> 2, tc = (tid & 3) * 16;
  bf16x8 o0, o1;
#pragma unroll
  for (int j = 0; j < 8; j++) { o0[j] = tile[tc + j][d]; o1[j] = tile[tc + 8 + j][d]; }
  __bf16* dst = vt + ((size_t)bh * HD + d) * TT + tt * 64 + tc;
  *(bf16x8*)dst = o0;
  *(bf16x8*)(dst + 8) = o1;
}

// ---------------------------------------------------------------------------
// Causal flash attention v11 = v9 structure, V staging removed (m169 lesson).
//   - K: 4-deep LDS buffers via gload_lds (2 loads/thread/stage), counted
//     s_waitcnt vmcnt(2) at iter end (K(t+3)'s loads stay in flight across
//     the barrier; K(t+1) guaranteed landed for next iter's QK).
//   - V: read as B-fragments DIRECTLY from global Vt (L2-resident: 4 heads
//     x 512KB = 2MB per XCD < 4MB). vb loads issued at iter start; latency
//     hides under QK(t+1)'s LDS reads + MFMAs.
//   - LDS 40KB -> 4 blocks/CU (16 waves/CU cap, 2x v9). VGPR <= 128.
//   - Pipeline per iter t: loadV(t) | stageK(t+3) | QK(t+1) | PV(t) |
//     softmax(t+1). P round-trip spans a full phase as in v9.
// grid = 1024 (32 chunks x 32 bh), LPT order (longest first).
// ---------------------------------------------------------------------------
__device__ __forceinline__ int psw(int row) {
  return (((row & 7) ^ ((row >> 3) & 7))) << 4;
}

__global__ __launch_bounds__(256, 4)
void attn_causal11(const __bf16* __restrict__ qkv, const __bf16* __restrict__ vt,
                   __bf16* __restrict__ yb) {
  __shared__ __align__(16) char Kbuf[4][8192];   // K[kv][d], chunk-swizzled
  __shared__ __align__(16) char Pbuf[4][2048];   // per-wave P[16][64], psw-swizzled

  const int tid = threadIdx.x;
  const int lane = tid & 63, w = tid >> 6;
  const int L = blockIdx.x;
  const int bh = L & 31;
  const int chunk = 31 - (L >> 5);               // LPT: longest first
  const int b = bh >> 4, h = bh & 15;
  const size_t rowbase = (size_t)b * TT;
  const int q0 = chunk * 64 + w * 16;
  const int fr = lane & 15, g = lane >> 4;
  const int ntiles = chunk + 1;

  bf16x8 qf[2];
#pragma unroll
  for (int kc = 0; kc < 2; kc++)
    qf[kc] = *(const bf16x8*)(qkv + (rowbase + q0 + fr) * QKVN + h * HD + kc * 32 + g * 8);

  bf16x8 ones;
#pragma unroll
  for (int j = 0; j < 8; j++) ones[j] = (__bf16)1.0f;

  // per-lane Vt row base pointers (row d = n*16+fr, col base g*8)
  const __bf16* vp[4];
#pragma unroll
  for (int n = 0; n < 4; n++)
    vp[n] = vt + ((size_t)bh * HD + n * 16 + fr) * TT + g * 8;

  f32x4 o[4];
  f32x4 lacc;
  float m[4];
#pragma unroll
  for (int n = 0; n < 4; n++)
#pragma unroll
    for (int r = 0; r < 4; r++) o[n][r] = 0.0f;
#pragma unroll
  for (int r = 0; r < 4; r++) { lacc[r] = 0.0f; m[r] = -1e30f; }

  // 2 gload_lds per thread per stage -> vmcnt(2) = one K-stage in flight
  auto stageK = [&](int kt, int buf) {
#pragma unroll
    for (int i = 0; i < 2; i++) {
      const int c = tid + i * 256;
      const int row = c >> 3;
      const int c16 = (c & 7) ^ (row & 7);
      gload_lds16(qkv + (rowbase + kt * 64 + row) * QKVN + EMB + h * HD + c16 * 8,
                  Kbuf[buf] + c * 16);
    }
  };

  // V fragments direct from global (L2): vb[n][kc] covers d=n*16+fr,
  // kv = t*64 + kc*32 + g*8..+7  (layout verified in v10)
  auto loadV = [&](int t, bf16x8 (&vb)[4][2]) {
    const int off = t * 64;
#pragma unroll
    for (int n = 0; n < 4; n++) {
      vb[n][0] = *(const bf16x8*)(vp[n] + off);
      vb[n][1] = *(const bf16x8*)(vp[n] + off + 32);
    }
  };

  auto doQK = [&](int kt, f32x4 (&s)[4]) {
    const char* Kc = Kbuf[kt & 3];
    bf16x8 kf[4][2];
#pragma unroll
    for (int n = 0; n < 4; n++)
#pragma unroll
      for (int kc = 0; kc < 2; kc++) {
        const int row = n * 16 + fr;
        kf[n][kc] = *(const bf16x8*)(Kc + row * 128 + (((kc << 2) | g) ^ (row & 7)) * 16);
      }
#pragma unroll
    for (int n = 0; n < 4; n++) {
#pragma unroll
      for (int r = 0; r < 4; r++) s[n][r] = 0.0f;
#pragma unroll
      for (int kc = 0; kc < 2; kc++)
        s[n] = __builtin_amdgcn_mfma_f32_16x16x32_bf16(qf[kc], kf[n][kc], s[n], 0, 0, 0);
    }
  };

  auto doSoftmax = [&](int kt, f32x4 (&s)[4]) {
    const int kv0 = kt * 64;
    if (kt == chunk) {
#pragma unroll
      for (int n = 0; n < 4; n++)
#pragma unroll
        for (int r = 0; r < 4; r++) {
          const int qg = q0 + g * 4 + r;
          const int kg = kv0 + n * 16 + fr;
          if (kg > qg) s[n][r] = -1e30f;
        }
    }
    float pm[4];
#pragma unroll
    for (int r = 0; r < 4; r++)
      pm[r] = fmaxf(fmaxf(s[0][r], s[1][r]), fmaxf(s[2][r], s[3][r]));
    const bool ok = (pm[0] <= m[0] + THR) && (pm[1] <= m[1] + THR) &&
                    (pm[2] <= m[2] + THR) && (pm[3] <= m[3] + THR);
    if (!__all(ok)) {
#pragma unroll
      for (int r = 0; r < 4; r++) {
        float rm = pm[r];
#pragma unroll
        for (int d = 1; d < 16; d <<= 1) rm = fmaxf(rm, __shfl_xor(rm, d, 16));
        const float nm = fmaxf(m[r], rm);
        const float f = __builtin_amdgcn_exp2f(m[r] - nm);
        m[r] = nm;
        lacc[r] *= f;
#pragma unroll
        for (int n = 0; n < 4; n++) o[n][r] *= f;
      }
    }
#pragma unroll
    for (int n = 0; n < 4; n++)
#pragma unroll
      for (int r = 0; r < 4; r++) {
        const float e = __builtin_amdgcn_exp2f(s[n][r] - m[r]);
        const int row = g * 4 + r;
        *(__bf16*)(Pbuf[w] + row * 128 + (((n * 16 + fr) * 2) ^ psw(row))) = (__bf16)e;
      }
  };

  auto doPV = [&](bf16x8 (&vb)[4][2]) {
    bf16x8 pa[2];
#pragma unroll
    for (int kc = 0; kc < 2; kc++)
      pa[kc] = *(const bf16x8*)(Pbuf[w] + fr * 128 + ((kc * 64 + g * 16) ^ psw(fr)));
#pragma unroll
    for (int kc = 0; kc < 2; kc++) {
      lacc = __builtin_amdgcn_mfma_f32_16x16x32_bf16(pa[kc], ones, lacc, 0, 0, 0);
#pragma unroll
      for (int n = 0; n < 4; n++)
        o[n] = __builtin_amdgcn_mfma_f32_16x16x32_bf16(pa[kc], vb[n][kc], o[n], 0, 0, 0);
    }
  };

  // ---- prologue: stage K tiles 0..2; force tile 0 landed ----
  stageK(0, 0);
  if (ntiles > 1) stageK(1, 1);
  if (ntiles > 2) stageK(2, 2);
  if (ntiles > 2) asm volatile("s_waitcnt vmcnt(4)" ::: "memory");
  else            asm volatile("s_waitcnt vmcnt(0)" ::: "memory");
  __builtin_amdgcn_s_barrier();

  {                                   // tile 0: QK + softmax (P ready for loop)
    f32x4 s0[4];
    doQK(0, s0);
    doSoftmax(0, s0);
  }

  for (int t = 0; t < ntiles; t++) {
    bf16x8 vb[4][2];
    loadV(t, vb);                     // issue early: hides under QK(t+1)
    if (t + 3 < ntiles) stageK(t + 3, (t + 3) & 3);

    const bool nxt = (t + 1 < ntiles);
    f32x4 s[4];
    if (nxt) doQK(t + 1, s);          // overlaps vb L2 latency
    doPV(vb);                         // consumes P(t) + vb(t)
    if (nxt) doSoftmax(t + 1, s);     // rescale o AFTER PV(t); writes P(t+1)

    // counted wait: K(t+1) landed for next iter; K(t+3)'s 2 loads float
    if (t + 3 < ntiles) asm volatile("s_waitcnt vmcnt(2)" ::: "memory");
    else                asm volatile("s_waitcnt vmcnt(0)" ::: "memory");
    __builtin_amdgcn_s_barrier();
  }

#pragma unroll
  for (int r = 0; r < 4; r++) {
    const float inv = __builtin_amdgcn_rcpf(lacc[r]);
#pragma unroll
    for (int n = 0; n < 4; n++) {
      const int q = q0 + g * 4 + r;
      const int d = n * 16 + fr;
      yb[(rowbase + q) * EMB + h * HD + d] = (__bf16)(o[n][r] * inv);
    }
  }
}

extern "C" void kernel_launch(void* const* d_in, const int* in_sizes, int n_in,
                              void* d_out, int out_size, void* d_ws, size_t ws_size,
                              hipStream_t stream) {
  const float* x     = (const float*)d_in[0];
  const float* w_qkv = (const float*)d_in[1];
  const float* w_out = (const float*)d_in[2];
  float* out = (float*)d_out;

  char* ws = (char*)d_ws;
  __bf16* xb    = (__bf16*)(ws);                 // reused as Vt after gemm1
  __bf16* wqkvb = (__bf16*)(ws + (8ull  << 20));
  __bf16* wob   = (__bf16*)(ws + (14ull << 20));
  __bf16* qkvb  = (__bf16*)(ws + (16ull << 20));
  __bf16* yb    = (__bf16*)(ws + (40ull << 20));
  __bf16* vtb   = xb;

  cvt_all<<<4096, 256, 0, stream>>>(x, w_qkv, w_out, xb, wqkvb, wob);
  gemm_bt<1, 1><<<dim3(QKVN / 128, NROWS / 128), 256, 0, stream>>>(xb, wqkvb, qkvb, NROWS, QKVN, EMB);
  vtrans<<<dim3(TT / 64, 32), 256, 0, stream>>>(qkvb, vtb);
  attn_causal11<<<1024, 256, 0, stream>>>(qkvb, vtb, yb);
  gemm_bt<0, 0><<<dim3(EMB / 128, NROWS / 128), 256, 0, stream>>>(yb, wob, out, NROWS, EMB, EMB);
}

// Round 12
// 102.355 us; speedup vs baseline: 1.9619x; 1.7297x over previous
//
#include <hip/hip_runtime.h>
#include <hip/hip_bf16.h>
#include <cstdint>

// ---------------------------------------------------------------------------
// Fused causal self-attention block (B=2, T=2048, C=1024, H=16, Dh=64), fp32 in/out.
// cvt fp32->bf16 -> QKV GEMM (Q pre-scaled, V written transposed) -> flash attn -> out GEMM.
// Workspace (48MB):
//   yb    @ 0     8 MB   bf16 x [4096][1024] (xb) -> DEAD after gemm1 -> reused as yb
//   wqkvb @ 8 MB  6 MB   bf16 w_qkv [3072][1024]
//   wob   @ 14MB  2 MB   bf16 w_out [1024][1024]
//   qkvb  @ 16MB 24 MB   bf16 qkv [4096][3072] (Q scaled | K | V-region unused)
//   vt    @ 40MB  8 MB   bf16 Vt [32 bh][64 d][2048 t] (written by gemm1 epilogue)
// ---------------------------------------------------------------------------

typedef __bf16 bf16x8 __attribute__((ext_vector_type(8)));
typedef float  f32x4  __attribute__((ext_vector_type(4)));
typedef unsigned short u16x4 __attribute__((ext_vector_type(4)));

#define EMB   1024
#define HEADS 16
#define HD    64
#define TT    2048
#define NROWS 4096
#define QKVN  3072
#define SCL   0.18033688f   /* 0.125 * log2(e): folded into Q at gemm1 epilogue */
#define THR   11.0f         /* defer-max threshold, log2 units */

// ---- fused fp32 -> bf16 (8 elems / thread, 3 arrays in one launch) ----
__global__ void cvt_all(const float* __restrict__ x, const float* __restrict__ wq,
                        const float* __restrict__ wo, __bf16* __restrict__ xb,
                        __bf16* __restrict__ wqb, __bf16* __restrict__ wob) {
  const int bid = blockIdx.x;
  const float* in; __bf16* out; int i;
  if (bid < 2048)      { in = x;  out = xb;  i = bid * 256 + threadIdx.x; }
  else if (bid < 3584) { in = wq; out = wqb; i = (bid - 2048) * 256 + threadIdx.x; }
  else                 { in = wo; out = wob; i = (bid - 3584) * 256 + threadIdx.x; }
  const float4* p = (const float4*)in + (size_t)i * 2;
  float4 a = p[0], b = p[1];
  bf16x8 o;
  o[0] = (__bf16)a.x; o[1] = (__bf16)a.y; o[2] = (__bf16)a.z; o[3] = (__bf16)a.w;
  o[4] = (__bf16)b.x; o[5] = (__bf16)b.y; o[6] = (__bf16)b.z; o[7] = (__bf16)b.w;
  *((bf16x8*)out + i) = o;
}

__device__ __forceinline__ void gload_lds16(const void* g, void* l) {
  __builtin_amdgcn_global_load_lds(
      (const __attribute__((address_space(1))) void*)(uintptr_t)g,
      (__attribute__((address_space(3))) void*)(uint32_t)(uintptr_t)l,
      16, 0, 0);
}

// ---------------------------------------------------------------------------
// GEMM v2: C[M,N] = A[M,K]*Bm[N,K]^T, 128x128 tile, BK=64 (128B LDS rows),
// chunk-swizzled staging (source pre-swizzle c^(row&7), linear dest) ->
// all ds_read_b128 conflict-free (2-way). XCD-bijective block swizzle.
// MODE 0: fp32 out (plain). MODE 1 (QKV): cols<1024 scaled by SCL -> bf16
// qkvb; cols 1024..2047 plain bf16 qkvb; cols>=2048 (V) written TRANSPOSED
// to vt[bh][d][t] as packed 8B stores (vtrans kernel eliminated).
// ---------------------------------------------------------------------------
template <int MODE>
__global__ __launch_bounds__(256, 2)
void gemm_bt(const __bf16* __restrict__ A, const __bf16* __restrict__ Bm,
             void* __restrict__ Cout, __bf16* __restrict__ vt,
             int M, int N, int K) {
  __shared__ __align__(16) char As[128 * 128];   // [128 rows][64 K] bf16, swizzled
  __shared__ __align__(16) char Bs[128 * 128];
  const int tid  = threadIdx.x;
  const int lane = tid & 63;
  const int wid  = tid >> 6;
  const int wr = wid >> 1, wc = wid & 1;
  const int nwg = gridDim.x * gridDim.y;
  int flat = blockIdx.y * gridDim.x + blockIdx.x;
  flat = (flat & 7) * (nwg >> 3) + (flat >> 3);
  const int brow = (flat / gridDim.x) * 128;
  const int bcol = (flat % gridDim.x) * 128;
  const int fr = lane & 15, g = lane >> 4;

  f32x4 acc[4][4];
#pragma unroll
  for (int m = 0; m < 4; m++)
#pragma unroll
    for (int n = 0; n < 4; n++)
#pragma unroll
      for (int r = 0; r < 4; r++) acc[m][n][r] = 0.0f;

  for (int k0 = 0; k0 < K; k0 += 64) {
    __syncthreads();
#pragma unroll
    for (int i = 0; i < 4; i++) {                // 1024 chunks per tile, 256 thr
      const int c = tid + i * 256;
      const int row = c >> 3, pos = c & 7;
      const int sc = pos ^ (row & 7);            // source chunk (pre-swizzle)
      gload_lds16(A  + (size_t)(brow + row) * K + k0 + sc * 8, As + c * 16);
      gload_lds16(Bm + (size_t)(bcol + row) * K + k0 + sc * 8, Bs + c * 16);
    }
    __syncthreads();

    bf16x8 af[4][2], bfr[4][2];
#pragma unroll
    for (int m = 0; m < 4; m++)
#pragma unroll
      for (int kc = 0; kc < 2; kc++) {
        const int row = wr * 64 + m * 16 + fr;
        af[m][kc] = *(const bf16x8*)(As + row * 128 + (((kc << 2) | g) ^ (fr & 7)) * 16);
      }
#pragma unroll
    for (int n = 0; n < 4; n++)
#pragma unroll
      for (int kc = 0; kc < 2; kc++) {
        const int row = wc * 64 + n * 16 + fr;
        bfr[n][kc] = *(const bf16x8*)(Bs + row * 128 + (((kc << 2) | g) ^ (fr & 7)) * 16);
      }
#pragma unroll
    for (int kc = 0; kc < 2; kc++)
#pragma unroll
      for (int m = 0; m < 4; m++)
#pragma unroll
        for (int n = 0; n < 4; n++)
          acc[m][n] = __builtin_amdgcn_mfma_f32_16x16x32_bf16(af[m][kc], bfr[n][kc], acc[m][n], 0, 0, 0);
  }

  const int rbase = brow + wr * 64 + g * 4;
  const int cbase = bcol + wc * 64 + fr;
  if (MODE == 0) {
#pragma unroll
    for (int m = 0; m < 4; m++)
#pragma unroll
      for (int n = 0; n < 4; n++) {
        const int col = cbase + n * 16;
#pragma unroll
        for (int r = 0; r < 4; r++)
          ((float*)Cout)[(size_t)(rbase + m * 16 + r) * N + col] = acc[m][n][r];
      }
  } else if (bcol < 2 * EMB) {
    // Q (scaled) / K (plain) -> qkvb bf16
    const float qscale = (bcol < EMB) ? SCL : 1.0f;
#pragma unroll
    for (int m = 0; m < 4; m++)
#pragma unroll
      for (int n = 0; n < 4; n++) {
        const int col = cbase + n * 16;
#pragma unroll
        for (int r = 0; r < 4; r++)
          ((__bf16*)Cout)[(size_t)(rbase + m * 16 + r) * N + col] = (__bf16)(acc[m][n][r] * qscale);
      }
  } else {
    // V -> vt[bh][d][t], transposed; 4 consecutive t packed into one 8B store
#pragma unroll
    for (int m = 0; m < 4; m++) {
      const int row0 = rbase + m * 16;           // 4-aligned
      const int b = row0 >> 11, t0 = row0 & 2047;
#pragma unroll
      for (int n = 0; n < 4; n++) {
        const int vcol = cbase + n * 16 - 2 * EMB;
        const int bh = b * HEADS + (vcol >> 6);
        const int d  = vcol & 63;
        u16x4 pk;
#pragma unroll
        for (int r = 0; r < 4; r++) {
          const __bf16 h = (__bf16)acc[m][n][r];
          pk[r] = *(const unsigned short*)&h;
        }
        *(u16x4*)(vt + ((size_t)bh * HD + d) * TT + t0) = pk;
      }
    }
  }
}

// ---------------------------------------------------------------------------
// Causal flash attention (v9, best measured): cross-tile software pipeline.
//   Iter t: stage(t+3) | QK(t+1) | PV(t) | softmax(t+1)+P-write(t+1).
//   4-deep K/V LDS buffers, counted s_waitcnt vmcnt(4) (never 0 in steady
//   state); raw v_exp_f32; defer-max vote; row-sum via ones-MFMA;
//   Q pre-scaled at gemm1. grid = 1024 (32 chunks x 32 bh), LPT order.
// ---------------------------------------------------------------------------
__device__ __forceinline__ int psw(int row) {
  return (((row & 7) ^ ((row >> 3) & 7))) << 4;
}

__global__ __launch_bounds__(256, 2)
void attn_causal9(const __bf16* __restrict__ qkv, const __bf16* __restrict__ vt,
                  __bf16* __restrict__ yb) {
  __shared__ __align__(16) char Kbuf[4][8192];   // K[kv][d], chunk-swizzled
  __shared__ __align__(16) char Vbuf[4][8192];   // Vt[d][kv], chunk-swizzled
  __shared__ __align__(16) char Pbuf[4][2048];   // per-wave P[16][64], psw-swizzled

  const int tid = threadIdx.x;
  const int lane = tid & 63, w = tid >> 6;
  const int L = blockIdx.x;
  const int bh = L & 31;
  const int chunk = 31 - (L >> 5);               // LPT: longest first
  const int b = bh >> 4, h = bh & 15;
  const size_t rowbase = (size_t)b * TT;
  const int q0 = chunk * 64 + w * 16;
  const int fr = lane & 15, g = lane >> 4;
  const int ntiles = chunk + 1;

  bf16x8 qf[2];
#pragma unroll
  for (int kc = 0; kc < 2; kc++)
    qf[kc] = *(const bf16x8*)(qkv + (rowbase + q0 + fr) * QKVN + h * HD + kc * 32 + g * 8);

  bf16x8 ones;
#pragma unroll
  for (int j = 0; j < 8; j++) ones[j] = (__bf16)1.0f;

  f32x4 o[4];
  f32x4 lacc;
  float m[4];
#pragma unroll
  for (int n = 0; n < 4; n++)
#pragma unroll
    for (int r = 0; r < 4; r++) o[n][r] = 0.0f;
#pragma unroll
  for (int r = 0; r < 4; r++) { lacc[r] = 0.0f; m[r] = -1e30f; }

  auto stageKV = [&](int kt, int buf) {
#pragma unroll
    for (int i = 0; i < 2; i++) {
      const int c = tid + i * 256;
      const int row = c >> 3;
      const int c16 = (c & 7) ^ (row & 7);
      gload_lds16(qkv + (rowbase + kt * 64 + row) * QKVN + EMB + h * HD + c16 * 8,
                  Kbuf[buf] + c * 16);
    }
#pragma unroll
    for (int i = 0; i < 2; i++) {
      const int c = tid + i * 256;
      const int row = c >> 3;
      const int c16 = (c & 7) ^ (row & 7);
      gload_lds16(vt + ((size_t)bh * HD + row) * TT + kt * 64 + c16 * 8,
                  Vbuf[buf] + c * 16);
    }
  };

  auto doQK = [&](int kt, f32x4 (&s)[4]) {
    const char* Kc = Kbuf[kt & 3];
    bf16x8 kf[4][2];
#pragma unroll
    for (int n = 0; n < 4; n++)
#pragma unroll
      for (int kc = 0; kc < 2; kc++) {
        const int row = n * 16 + fr;
        kf[n][kc] = *(const bf16x8*)(Kc + row * 128 + (((kc << 2) | g) ^ (row & 7)) * 16);
      }
#pragma unroll
    for (int n = 0; n < 4; n++) {
#pragma unroll
      for (int r = 0; r < 4; r++) s[n][r] = 0.0f;
#pragma unroll
      for (int kc = 0; kc < 2; kc++)
        s[n] = __builtin_amdgcn_mfma_f32_16x16x32_bf16(qf[kc], kf[n][kc], s[n], 0, 0, 0);
    }
  };

  auto doSoftmax = [&](int kt, f32x4 (&s)[4]) {
    const int kv0 = kt * 64;
    if (kt == chunk) {
#pragma unroll
      for (int n = 0; n < 4; n++)
#pragma unroll
        for (int r = 0; r < 4; r++) {
          const int qg = q0 + g * 4 + r;
          const int kg = kv0 + n * 16 + fr;
          if (kg > qg) s[n][r] = -1e30f;
        }
    }
    float pm[4];
#pragma unroll
    for (int r = 0; r < 4; r++)
      pm[r] = fmaxf(fmaxf(s[0][r], s[1][r]), fmaxf(s[2][r], s[3][r]));
    const bool ok = (pm[0] <= m[0] + THR) && (pm[1] <= m[1] + THR) &&
                    (pm[2] <= m[2] + THR) && (pm[3] <= m[3] + THR);
    if (!__all(ok)) {
#pragma unroll
      for (int r = 0; r < 4; r++) {
        float rm = pm[r];
#pragma unroll
        for (int d = 1; d < 16; d <<= 1) rm = fmaxf(rm, __shfl_xor(rm, d, 16));
        const float nm = fmaxf(m[r], rm);
        const float f = __builtin_amdgcn_exp2f(m[r] - nm);
        m[r] = nm;
        lacc[r] *= f;
#pragma unroll
        for (int n = 0; n < 4; n++) o[n][r] *= f;
      }
    }
#pragma unroll
    for (int n = 0; n < 4; n++)
#pragma unroll
      for (int r = 0; r < 4; r++) {
        const float e = __builtin_amdgcn_exp2f(s[n][r] - m[r]);
        const int row = g * 4 + r;
        *(__bf16*)(Pbuf[w] + row * 128 + (((n * 16 + fr) * 2) ^ psw(row))) = (__bf16)e;
      }
  };

  auto doPV = [&](int kt) {
    const char* Vc = Vbuf[kt & 3];
    bf16x8 pa[2];
#pragma unroll
    for (int kc = 0; kc < 2; kc++)
      pa[kc] = *(const bf16x8*)(Pbuf[w] + fr * 128 + ((kc * 64 + g * 16) ^ psw(fr)));
    bf16x8 vb[4][2];
#pragma unroll
    for (int n = 0; n < 4; n++)
#pragma unroll
      for (int kc = 0; kc < 2; kc++) {
        const int row = n * 16 + fr;
        vb[n][kc] = *(const bf16x8*)(Vc + row * 128 + (((kc << 2) | g) ^ (row & 7)) * 16);
      }
#pragma unroll
    for (int kc = 0; kc < 2; kc++) {
      lacc = __builtin_amdgcn_mfma_f32_16x16x32_bf16(pa[kc], ones, lacc, 0, 0, 0);
#pragma unroll
      for (int n = 0; n < 4; n++)
        o[n] = __builtin_amdgcn_mfma_f32_16x16x32_bf16(pa[kc], vb[n][kc], o[n], 0, 0, 0);
    }
  };

  // ---- prologue: fill pipeline (tiles 0..2), force 0,1 landed ----
  stageKV(0, 0);
  if (ntiles > 1) stageKV(1, 1);
  if (ntiles > 2) stageKV(2, 2);
  if (ntiles > 2) asm volatile("s_waitcnt vmcnt(4)" ::: "memory");
  else            asm volatile("s_waitcnt vmcnt(0)" ::: "memory");
  __builtin_amdgcn_s_barrier();

  {                                   // tile 0: QK + softmax (P ready for loop)
    f32x4 s0[4];
    doQK(0, s0);
    doSoftmax(0, s0);
  }

  for (int t = 0; t < ntiles; t++) {
    if (t + 3 < ntiles) stageKV(t + 3, (t + 3) & 3);

    const bool nxt = (t + 1 < ntiles);
    f32x4 s[4];
    if (nxt) doQK(t + 1, s);          // independent stream: overlaps PV(t)
    doPV(t);                          // consumes P(t) written last iter
    if (nxt) doSoftmax(t + 1, s);     // rescale o AFTER PV(t); writes P(t+1)

    if (t + 3 < ntiles) asm volatile("s_waitcnt vmcnt(4)" ::: "memory");
    else                asm volatile("s_waitcnt vmcnt(0)" ::: "memory");
    __builtin_amdgcn_s_barrier();
  }

#pragma unroll
  for (int r = 0; r < 4; r++) {
    const float inv = __builtin_amdgcn_rcpf(lacc[r]);
#pragma unroll
    for (int n = 0; n < 4; n++) {
      const int q = q0 + g * 4 + r;
      const int d = n * 16 + fr;
      yb[(rowbase + q) * EMB + h * HD + d] = (__bf16)(o[n][r] * inv);
    }
  }
}

extern "C" void kernel_launch(void* const* d_in, const int* in_sizes, int n_in,
                              void* d_out, int out_size, void* d_ws, size_t ws_size,
                              hipStream_t stream) {
  const float* x     = (const float*)d_in[0];
  const float* w_qkv = (const float*)d_in[1];
  const float* w_out = (const float*)d_in[2];
  float* out = (float*)d_out;

  char* ws = (char*)d_ws;
  __bf16* xb    = (__bf16*)(ws);                 // dead after gemm1 -> reused as yb
  __bf16* wqkvb = (__bf16*)(ws + (8ull  << 20));
  __bf16* wob   = (__bf16*)(ws + (14ull << 20));
  __bf16* qkvb  = (__bf16*)(ws + (16ull << 20));
  __bf16* vtb   = (__bf16*)(ws + (40ull << 20));
  __bf16* yb    = xb;

  cvt_all<<<4096, 256, 0, stream>>>(x, w_qkv, w_out, xb, wqkvb, wob);
  // QKV GEMM: writes Q (scaled) + K to qkvb, V transposed to vtb
  gemm_bt<1><<<dim3(QKVN / 128, NROWS / 128), 256, 0, stream>>>(xb, wqkvb, qkvb, vtb, NROWS, QKVN, EMB);
  attn_causal9<<<1024, 256, 0, stream>>>(qkvb, vtb, yb);
  gemm_bt<0><<<dim3(EMB / 128, NROWS / 128), 256, 0, stream>>>(yb, wob, out, nullptr, NROWS, EMB, EMB);
}